// Round 1
// baseline (258.673 us; speedup 1.0000x reference)
//
#include <hip/hip_runtime.h>

#define TILE 32
#define PAD 5
#define HALO (TILE + 2 * PAD)   // 42
#define KW 11
#define IMG 512
#define NPLANES 48              // 16 batch * 3 channels

// Fused SSIM: per block = one 32x32 output tile of one (n,c) plane.
// Separable 11x11 Gaussian blur of {a, b, a^2, b^2, ab} via LDS,
// then SSIM map + block reduction + atomicAdd(double) partial sum.
__global__ __launch_bounds__(256) void ssim_fused_kernel(
    const float* __restrict__ img1,
    const float* __restrict__ img2,
    double* __restrict__ accum)
{
    __shared__ float sA[HALO][HALO + 2];   // stride 44 floats
    __shared__ float sB[HALO][HALO + 2];
    __shared__ float h[5][HALO][TILE];     // horizontal-blurred quantities
    __shared__ float wave_sums[4];

    // Normalized 1D gaussian weights (separable; exact product = jnp's 2D/sum).
    float w[KW];
    {
        float s = 0.f;
#pragma unroll
        for (int i = 0; i < KW; ++i) {
            float d = (float)(i - PAD);
            w[i] = expf(-(d * d) / 4.5f);   // 2*sigma^2 = 4.5
            s += w[i];
        }
#pragma unroll
        for (int i = 0; i < KW; ++i) w[i] /= s;
    }

    const int plane = blockIdx.z;
    const int tile_x = blockIdx.x * TILE;
    const int tile_y = blockIdx.y * TILE;
    const float* __restrict__ A = img1 + (size_t)plane * IMG * IMG;
    const float* __restrict__ B = img2 + (size_t)plane * IMG * IMG;

    const int tid = threadIdx.x;

    // ---- stage halos (zero padding outside image) ----
    for (int i = tid; i < HALO * HALO; i += 256) {
        int r = i / HALO, c = i - r * HALO;
        int gy = tile_y + r - PAD;
        int gx = tile_x + c - PAD;
        bool inb = (gy >= 0) && (gy < IMG) && (gx >= 0) && (gx < IMG);
        size_t idx = (size_t)gy * IMG + gx;
        sA[r][c] = inb ? A[idx] : 0.f;
        sB[r][c] = inb ? B[idx] : 0.f;
    }
    __syncthreads();

    // ---- horizontal 11-tap pass over 42 rows x 32 cols ----
    for (int i = tid; i < HALO * TILE; i += 256) {
        int r = i / TILE, c = i - r * TILE;
        float s0 = 0.f, s1 = 0.f, s2 = 0.f, s3 = 0.f, s4 = 0.f;
#pragma unroll
        for (int k = 0; k < KW; ++k) {
            float a = sA[r][c + k];
            float b = sB[r][c + k];
            float wk = w[k];
            s0 += wk * a;
            s1 += wk * b;
            s2 += wk * (a * a);
            s3 += wk * (b * b);
            s4 += wk * (a * b);
        }
        h[0][r][c] = s0;
        h[1][r][c] = s1;
        h[2][r][c] = s2;
        h[3][r][c] = s3;
        h[4][r][c] = s4;
    }
    __syncthreads();

    // ---- vertical 11-tap pass + SSIM map ----
    const float C1 = 1e-4f;    // 0.01^2
    const float C2 = 9e-4f;    // 0.03^2
    float local = 0.f;
    for (int i = tid; i < TILE * TILE; i += 256) {
        int r = i / TILE, c = i - r * TILE;
        float mu1 = 0.f, mu2 = 0.f, x11 = 0.f, x22 = 0.f, x12 = 0.f;
#pragma unroll
        for (int k = 0; k < KW; ++k) {
            float wk = w[k];
            mu1 += wk * h[0][r + k][c];
            mu2 += wk * h[1][r + k][c];
            x11 += wk * h[2][r + k][c];
            x22 += wk * h[3][r + k][c];
            x12 += wk * h[4][r + k][c];
        }
        float mu1s = mu1 * mu1;
        float mu2s = mu2 * mu2;
        float m12  = mu1 * mu2;
        float s11 = x11 - mu1s;
        float s22 = x22 - mu2s;
        float s12 = x12 - m12;
        float num = (2.f * m12 + C1) * (2.f * s12 + C2);
        float den = (mu1s + mu2s + C1) * (s11 + s22 + C2);
        local += num / den;
    }

    // ---- block reduction ----
#pragma unroll
    for (int off = 32; off > 0; off >>= 1)
        local += __shfl_down(local, off);
    const int wave = tid >> 6;
    const int lane = tid & 63;
    if (lane == 0) wave_sums[wave] = local;
    __syncthreads();
    if (tid == 0) {
        float bs = wave_sums[0] + wave_sums[1] + wave_sums[2] + wave_sums[3];
        atomicAdd(accum, (double)bs);
    }
}

__global__ void ssim_finalize_kernel(const double* __restrict__ accum,
                                     float* __restrict__ out)
{
    const double N = (double)NPLANES * IMG * IMG;
    out[0] = (float)(1.0 - accum[0] / N);
}

extern "C" void kernel_launch(void* const* d_in, const int* in_sizes, int n_in,
                              void* d_out, int out_size, void* d_ws, size_t ws_size,
                              hipStream_t stream) {
    const float* img1 = (const float*)d_in[0];
    const float* img2 = (const float*)d_in[1];
    float* out = (float*)d_out;
    double* accum = (double*)d_ws;   // 8 bytes used

    // d_ws is poisoned 0xAA before every call — zero the accumulator.
    hipMemsetAsync(accum, 0, sizeof(double), stream);

    dim3 grid(IMG / TILE, IMG / TILE, NPLANES);  // 16 x 16 x 48
    ssim_fused_kernel<<<grid, 256, 0, stream>>>(img1, img2, accum);
    ssim_finalize_kernel<<<1, 1, 0, stream>>>(accum, out);
}

// Round 2
// 219.568 us; speedup vs baseline: 1.1781x; 1.1781x over previous
//
#include <hip/hip_runtime.h>

#define IMG 512
#define BW  256          // columns per block (1 per thread)
#define SH  64           // output rows per block
#define PAD 5
#define KW  11
#define NPLANES 48       // 16 batch * 3 channels
#define NCHUNK 7         // ceil((SH + 2*PAD) / KW) = ceil(74/11)

// Row-streaming fused SSIM.
// Block = 256 threads = 256 columns of a (BW x SH) output strip.
// Per input row: stage {a,b} row into LDS (double-buffered, 1 barrier/row),
// horizontal 11-tap blur of {a,b,a2,b2,ab} from LDS, then vertical blur via
// 5x11 REGISTER pending accumulators (slot = row mod 11, static via 11-phase
// unroll). Completed rows -> SSIM map -> per-thread sum -> atomicAdd(double).
__global__ __launch_bounds__(BW) void ssim_stream_kernel(
    const float* __restrict__ img1,
    const float* __restrict__ img2,
    double* __restrict__ accum)
{
    __shared__ float2 rAB[2][BW + 2 * PAD + 2];   // ~4.3 KB
    __shared__ float wave_sums[BW / 64];

    // Normalized 1D gaussian weights; broadcast to SGPRs.
    float w[KW];
    {
        float wv[KW];
        float s = 0.f;
#pragma unroll
        for (int i = 0; i < KW; ++i) {
            float d = (float)(i - PAD);
            wv[i] = expf(-(d * d) / 4.5f);   // 2*sigma^2 = 4.5
            s += wv[i];
        }
#pragma unroll
        for (int i = 0; i < KW; ++i)
            w[i] = __uint_as_float(
                __builtin_amdgcn_readfirstlane(__float_as_uint(wv[i] / s)));
    }

    const int plane = blockIdx.z;
    const int x0 = blockIdx.x * BW;
    const int y0 = blockIdx.y * SH;
    const float* __restrict__ A = img1 + (size_t)plane * (IMG * IMG);
    const float* __restrict__ B = img2 + (size_t)plane * (IMG * IMG);
    const int tid = threadIdx.x;

    // Pending vertical accumulators: 5 quantities x 11 slots (registers only;
    // all indices compile-time after unrolling).
    float acc0[KW], acc1[KW], acc2[KW], acc3[KW], acc4[KW];
#pragma unroll
    for (int j = 0; j < KW; ++j) {
        acc0[j] = 0.f; acc1[j] = 0.f; acc2[j] = 0.f; acc3[j] = 0.f; acc4[j] = 0.f;
    }

    // Staged columns for this thread (clamped addresses + zero select for pad).
    const int c0 = x0 - PAD + tid;
    const int cc0 = min(max(c0, 0), IMG - 1);
    const bool okc0 = (c0 >= 0) & (c0 < IMG);
    const int c1 = c0 + BW;
    const int cc1 = min(c1, IMG - 1);
    const bool okc1 = (c1 < IMG);

    const float C1v = 1e-4f;   // 0.01^2
    const float C2v = 9e-4f;   // 0.03^2
    float local = 0.f;

    int y = y0 - PAD;
    const int ylim = y0 + SH + PAD;   // one past last input row

#define SSIM_PHASE(p)                                                          \
    if (y < ylim) {                                                            \
        const int buf = y & 1;                                                 \
        {   /* stage input row y (zeros outside image) */                      \
            const int yy = min(max(y, 0), IMG - 1);                            \
            const bool oky = (y >= 0) & (y < IMG);                             \
            const size_t rowoff = (size_t)yy * IMG;                            \
            float va = A[rowoff + cc0];                                        \
            float vb = B[rowoff + cc0];                                        \
            const bool ok = oky & okc0;                                        \
            rAB[buf][tid] = make_float2(ok ? va : 0.f, ok ? vb : 0.f);         \
            if (tid < 2 * PAD) {                                               \
                float va2 = A[rowoff + cc1];                                   \
                float vb2 = B[rowoff + cc1];                                   \
                const bool ok2 = oky & okc1;                                   \
                rAB[buf][tid + BW] =                                           \
                    make_float2(ok2 ? va2 : 0.f, ok2 ? vb2 : 0.f);             \
            }                                                                  \
        }                                                                      \
        __syncthreads();                                                       \
        float h0 = 0.f, h1 = 0.f, h2 = 0.f, h3 = 0.f, h4 = 0.f;                \
        _Pragma("unroll")                                                      \
        for (int k = 0; k < KW; ++k) {                                         \
            const float2 ab = rAB[buf][tid + k];                               \
            const float a = ab.x, b = ab.y;                                    \
            h0 += w[k] * a;                                                    \
            h1 += w[k] * b;                                                    \
            h2 += w[k] * (a * a);                                              \
            h3 += w[k] * (b * b);                                              \
            h4 += w[k] * (a * b);                                              \
        }                                                                      \
        _Pragma("unroll")                                                      \
        for (int j = 0; j < KW; ++j) {                                         \
            const int sl = ((p) + j + 1) % KW;   /* slot of out row y-5+j */   \
            const float wj = w[10 - j];                                        \
            acc0[sl] += wj * h0;                                               \
            acc1[sl] += wj * h1;                                               \
            acc2[sl] += wj * h2;                                               \
            acc3[sl] += wj * h3;                                               \
            acc4[sl] += wj * h4;                                               \
        }                                                                      \
        {                                                                      \
            const int sd = ((p) + 1) % KW;       /* out row r = y-5 done */    \
            const int r = y - PAD;                                             \
            if (r >= y0) {                                                     \
                const float mu1 = acc0[sd], mu2 = acc1[sd];                    \
                const float x11 = acc2[sd], x22 = acc3[sd], x12 = acc4[sd];    \
                const float mu1s = mu1 * mu1, mu2s = mu2 * mu2;                \
                const float m12 = mu1 * mu2;                                   \
                const float num =                                             \
                    (2.f * m12 + C1v) * (2.f * (x12 - m12) + C2v);             \
                const float den = (mu1s + mu2s + C1v) *                        \
                                  ((x11 - mu1s) + (x22 - mu2s) + C2v);         \
                local += num * __builtin_amdgcn_rcpf(den);                     \
            }                                                                  \
            acc0[sd] = 0.f; acc1[sd] = 0.f; acc2[sd] = 0.f;                    \
            acc3[sd] = 0.f; acc4[sd] = 0.f;                                    \
        }                                                                      \
        ++y;                                                                   \
    }

#pragma unroll 1
    for (int chunk = 0; chunk < NCHUNK; ++chunk) {
        SSIM_PHASE(0) SSIM_PHASE(1) SSIM_PHASE(2) SSIM_PHASE(3)
        SSIM_PHASE(4) SSIM_PHASE(5) SSIM_PHASE(6) SSIM_PHASE(7)
        SSIM_PHASE(8) SSIM_PHASE(9) SSIM_PHASE(10)
    }
#undef SSIM_PHASE

    // ---- block reduction ----
#pragma unroll
    for (int off = 32; off > 0; off >>= 1)
        local += __shfl_down(local, off);
    if ((tid & 63) == 0) wave_sums[tid >> 6] = local;
    __syncthreads();
    if (tid == 0) {
        float bs = 0.f;
#pragma unroll
        for (int i = 0; i < BW / 64; ++i) bs += wave_sums[i];
        atomicAdd(accum, (double)bs);
    }
}

__global__ void ssim_finalize_kernel(const double* __restrict__ accum,
                                     float* __restrict__ out)
{
    const double N = (double)NPLANES * IMG * IMG;
    out[0] = (float)(1.0 - accum[0] / N);
}

extern "C" void kernel_launch(void* const* d_in, const int* in_sizes, int n_in,
                              void* d_out, int out_size, void* d_ws, size_t ws_size,
                              hipStream_t stream) {
    const float* img1 = (const float*)d_in[0];
    const float* img2 = (const float*)d_in[1];
    float* out = (float*)d_out;
    double* accum = (double*)d_ws;   // 8 bytes used

    // d_ws is poisoned 0xAA before every call — zero the accumulator.
    hipMemsetAsync(accum, 0, sizeof(double), stream);

    dim3 grid(IMG / BW, IMG / SH, NPLANES);   // 2 x 8 x 48 = 768 blocks
    ssim_stream_kernel<<<grid, BW, 0, stream>>>(img1, img2, accum);
    ssim_finalize_kernel<<<1, 1, 0, stream>>>(accum, out);
}

// Round 4
// 179.876 us; speedup vs baseline: 1.4381x; 1.2207x over previous
//
#include <hip/hip_runtime.h>

#define IMG 512
#define PAD 5
#define KW  11
#define SH  64                 // output rows per block strip
#define WCOLS 64               // output cols per wave
#define NWAVES 4
#define BW (WCOLS * NWAVES)    // 256 cols per block
#define STG (WCOLS + 2 * PAD)  // 74 staged cols per wave
#define NPLANES 48
#define NCHUNK 7               // 7*11 = 77 >= max 74 input rows

// Wave-independent row-streaming SSIM. No __syncthreads in the main loop:
// each wave stages its own 74-col {a,b} row into private LDS (in-order DS
// pipe makes same-wave write->read safe), prefetches the next row into
// registers, does the horizontal 11-tap blur from LDS, and scatters into
// 5x11 register vertical accumulators (slots compile-time via 11-phase
// unroll). Vertical zero-padding = simply skipping out-of-range rows.
__global__ __launch_bounds__(256) void ssim_wave_kernel(
    const float* __restrict__ img1,
    const float* __restrict__ img2,
    double* __restrict__ accum)
{
    __shared__ float2 sbuf[NWAVES][STG + 1];   // ~2.4 KB

    // Normalized 1D gaussian weights -> SGPRs.
    float w[KW];
    {
        float wv[KW];
        float s = 0.f;
#pragma unroll
        for (int i = 0; i < KW; ++i) {
            float d = (float)(i - PAD);
            wv[i] = expf(-(d * d) / 4.5f);     // 2*sigma^2 = 4.5
            s += wv[i];
        }
#pragma unroll
        for (int i = 0; i < KW; ++i)
            w[i] = __uint_as_float(
                __builtin_amdgcn_readfirstlane(__float_as_uint(wv[i] / s)));
    }

    const int tid   = threadIdx.x;
    const int wv_id = tid >> 6;
    const int lane  = tid & 63;
    const int plane = blockIdx.z;
    const int wc0   = blockIdx.x * BW + wv_id * WCOLS;
    const int y0    = blockIdx.y * SH;

    const float* __restrict__ A = img1 + (size_t)plane * (IMG * IMG);
    const float* __restrict__ B = img2 + (size_t)plane * (IMG * IMG);
    float2* lbuf = &sbuf[wv_id][0];

    // Per-thread column addressing (constant across rows).
    const int c0  = wc0 - PAD + lane;            // main staged col
    const int cc0 = min(max(c0, 0), IMG - 1);
    const float m0 = (c0 >= 0 && c0 < IMG) ? 1.f : 0.f;
    const int c1  = wc0 + (WCOLS - PAD) + lane;  // edge staged col (lane<10)
    const int cc1 = min(c1, IMG - 1);
    const float m1 = (c1 < IMG) ? 1.f : 0.f;

    const int ystart = max(y0 - PAD, 0);
    const int yend   = min(y0 + SH + PAD, IMG);

    // Vertical pending accumulators (registers; static indices only).
    float acc0[KW], acc1[KW], acc2[KW], acc3[KW], acc4[KW];
#pragma unroll
    for (int j = 0; j < KW; ++j) {
        acc0[j] = 0.f; acc1[j] = 0.f; acc2[j] = 0.f; acc3[j] = 0.f; acc4[j] = 0.f;
    }

    const float C1v = 1e-4f;
    const float C2v = 9e-4f;
    float local = 0.f;

    // Prefetch first row.
    const float* rowA = A + (size_t)ystart * IMG;
    const float* rowB = B + (size_t)ystart * IMG;
    float pa0 = rowA[cc0], pb0 = rowB[cc0];
    float pa1 = rowA[cc1], pb1 = rowB[cc1];

    int y = ystart;

    // SSIM evaluation of one completed slot (compile-time slot index).
#define SSIM_EMIT(sd)                                                          \
    {                                                                          \
        const float mu1 = acc0[sd], mu2 = acc1[sd];                            \
        const float x11 = acc2[sd], x22 = acc3[sd], x12 = acc4[sd];            \
        const float mu1s = mu1 * mu1, mu2s = mu2 * mu2;                        \
        const float m12 = mu1 * mu2;                                           \
        const float num = (2.f * m12 + C1v) * (2.f * (x12 - m12) + C2v);       \
        const float den = (mu1s + mu2s + C1v) *                                \
                          ((x11 - mu1s) + (x22 - mu2s) + C2v);                 \
        local += num * __builtin_amdgcn_rcpf(den);                             \
    }

#define SSIM_PHASE(p)                                                          \
    if (y < yend) {                                                            \
        /* stage current row (regs -> LDS, masked zeros for x-pad) */          \
        lbuf[lane] = make_float2(pa0 * m0, pb0 * m0);                          \
        if (lane < 2 * PAD)                                                    \
            lbuf[WCOLS + lane] = make_float2(pa1 * m1, pb1 * m1);              \
        /* prefetch next row into regs (latency hidden under compute) */       \
        if (y + 1 < yend) {                                                    \
            rowA += IMG; rowB += IMG;                                          \
            pa0 = rowA[cc0]; pb0 = rowB[cc0];                                  \
            pa1 = rowA[cc1]; pb1 = rowB[cc1];                                  \
        }                                                                      \
        /* horizontal 11-tap blur of {a,b,a2,b2,ab} */                         \
        float h0 = 0.f, h1 = 0.f, h2 = 0.f, h3 = 0.f, h4 = 0.f;                \
        _Pragma("unroll")                                                      \
        for (int k = 0; k < KW; ++k) {                                         \
            const float2 ab = lbuf[lane + k];                                  \
            const float a = ab.x, b = ab.y;                                    \
            h0 += w[k] * a;                                                    \
            h1 += w[k] * b;                                                    \
            h2 += w[k] * (a * a);                                              \
            h3 += w[k] * (b * b);                                              \
            h4 += w[k] * (a * b);                                              \
        }                                                                      \
        /* vertical scatter: input y -> outputs r=y-5+j, slot=(r-ystart)%11 */ \
        _Pragma("unroll")                                                      \
        for (int j = 0; j < KW; ++j) {                                         \
            const int sl = ((p) + 6 + j) % KW;                                 \
            const float wj = w[10 - j];                                        \
            acc0[sl] += wj * h0;                                               \
            acc1[sl] += wj * h1;                                               \
            acc2[sl] += wj * h2;                                               \
            acc3[sl] += wj * h3;                                               \
            acc4[sl] += wj * h4;                                               \
        }                                                                      \
        /* emit completed output row r = y-5 */                                \
        {                                                                      \
            const int sd = ((p) + 6) % KW;                                     \
            const int r = y - PAD;                                             \
            if (r >= y0) SSIM_EMIT(sd);                                        \
            acc0[sd] = 0.f; acc1[sd] = 0.f; acc2[sd] = 0.f;                    \
            acc3[sd] = 0.f; acc4[sd] = 0.f;                                    \
        }                                                                      \
        ++y;                                                                   \
    }

#pragma unroll 1
    for (int chunk = 0; chunk < NCHUNK; ++chunk) {
        SSIM_PHASE(0) SSIM_PHASE(1) SSIM_PHASE(2) SSIM_PHASE(3)
        SSIM_PHASE(4) SSIM_PHASE(5) SSIM_PHASE(6) SSIM_PHASE(7)
        SSIM_PHASE(8) SSIM_PHASE(9) SSIM_PHASE(10)
    }
#undef SSIM_PHASE

    // Bottom strip: rows 507..511 truncate at y=511; flush their slots.
    // ystart=443 -> slot(r)=(r-443)%11: 507->9, 508->10, 509->0, 510->1, 511->2.
    if (blockIdx.y == (IMG / SH - 1)) {
        SSIM_EMIT(9) SSIM_EMIT(10) SSIM_EMIT(0) SSIM_EMIT(1) SSIM_EMIT(2)
    }
#undef SSIM_EMIT

    // Per-wave reduction + one atomic per wave.
#pragma unroll
    for (int off = 32; off > 0; off >>= 1)
        local += __shfl_down(local, off);
    if (lane == 0)
        atomicAdd(accum, (double)local);
}

__global__ void ssim_finalize_kernel(const double* __restrict__ accum,
                                     float* __restrict__ out)
{
    const double N = (double)NPLANES * IMG * IMG;
    out[0] = (float)(1.0 - accum[0] / N);
}

extern "C" void kernel_launch(void* const* d_in, const int* in_sizes, int n_in,
                              void* d_out, int out_size, void* d_ws, size_t ws_size,
                              hipStream_t stream) {
    const float* img1 = (const float*)d_in[0];
    const float* img2 = (const float*)d_in[1];
    float* out = (float*)d_out;
    double* accum = (double*)d_ws;   // 8 bytes used

    // d_ws is poisoned 0xAA before every call — zero the accumulator.
    hipMemsetAsync(accum, 0, sizeof(double), stream);

    dim3 grid(IMG / BW, IMG / SH, NPLANES);   // 2 x 8 x 48 = 768 blocks
    ssim_wave_kernel<<<grid, BW, 0, stream>>>(img1, img2, accum);
    ssim_finalize_kernel<<<1, 1, 0, stream>>>(accum, out);
}

// Round 5
// 174.765 us; speedup vs baseline: 1.4801x; 1.0292x over previous
//
#include <hip/hip_runtime.h>

#define IMG 512
#define PAD 5
#define KW  11
#define SH  64                 // output rows per block strip
#define WCOLS 64               // output cols per wave
#define NWAVES 4
#define BW (WCOLS * NWAVES)    // 256 cols per block
#define STG (WCOLS + 2 * PAD)  // 74 staged cols per wave
#define NPLANES 48
#define NCHUNK 7               // 7*11 = 77 >= max 74 input rows

// Wave-independent row-streaming SSIM, spill-free variant.
// __launch_bounds__(256,4): VGPR budget 128 so the 4x11 register
// accumulator file stays in arch VGPRs (round-4's VGPR_Count=48 proved the
// 5x11 file was being spilled to AGPRs -> 3x VALU tax).
// 4-quantity trick: SSIM needs only blur{a, b, a^2+b^2, ab}:
//   s11+s22 = blur(a^2+b^2) - mu1^2 - mu2^2.
__global__ __launch_bounds__(256, 4) void ssim_wave_kernel(
    const float* __restrict__ img1,
    const float* __restrict__ img2,
    double* __restrict__ accum)
{
    __shared__ float2 sbuf[NWAVES][STG + 1];   // ~2.4 KB

    // Normalized 1D gaussian weights -> SGPRs.
    float w[KW];
    {
        float wv[KW];
        float s = 0.f;
#pragma unroll
        for (int i = 0; i < KW; ++i) {
            float d = (float)(i - PAD);
            wv[i] = expf(-(d * d) / 4.5f);     // 2*sigma^2 = 4.5
            s += wv[i];
        }
#pragma unroll
        for (int i = 0; i < KW; ++i)
            w[i] = __uint_as_float(
                __builtin_amdgcn_readfirstlane(__float_as_uint(wv[i] / s)));
    }

    const int tid   = threadIdx.x;
    const int wv_id = tid >> 6;
    const int lane  = tid & 63;
    const int plane = blockIdx.z;
    const int wc0   = blockIdx.x * BW + wv_id * WCOLS;
    const int y0    = blockIdx.y * SH;

    const float* __restrict__ A = img1 + (size_t)plane * (IMG * IMG);
    const float* __restrict__ B = img2 + (size_t)plane * (IMG * IMG);
    float2* lbuf = &sbuf[wv_id][0];

    // Per-thread column addressing (constant across rows).
    const int c0  = wc0 - PAD + lane;            // main staged col
    const int cc0 = min(max(c0, 0), IMG - 1);
    const float m0 = (c0 >= 0 && c0 < IMG) ? 1.f : 0.f;
    const int c1  = wc0 + (WCOLS - PAD) + lane;  // edge staged col (lane<10)
    const int cc1 = min(c1, IMG - 1);
    const float m1 = (c1 < IMG) ? 1.f : 0.f;

    const int ystart = max(y0 - PAD, 0);
    const int yend   = min(y0 + SH + PAD, IMG);

    // Vertical pending accumulators: 4 quantities x 11 slots, registers only.
    float acc0[KW], acc1[KW], acc2[KW], acc3[KW];
#pragma unroll
    for (int j = 0; j < KW; ++j) {
        acc0[j] = 0.f; acc1[j] = 0.f; acc2[j] = 0.f; acc3[j] = 0.f;
    }

    const float C1v = 1e-4f;
    const float C2v = 9e-4f;
    float local = 0.f;

    // Prefetch first row.
    const float* rowA = A + (size_t)ystart * IMG;
    const float* rowB = B + (size_t)ystart * IMG;
    float pa0 = rowA[cc0], pb0 = rowB[cc0];
    float pa1 = rowA[cc1], pb1 = rowB[cc1];

    int y = ystart;

    // SSIM evaluation of one completed slot (compile-time slot index).
#define SSIM_EMIT(sd)                                                          \
    {                                                                          \
        const float mu1 = acc0[sd], mu2 = acc1[sd];                            \
        const float xs  = acc2[sd], x12 = acc3[sd];                            \
        const float mu1s = mu1 * mu1, mu2s = mu2 * mu2;                        \
        const float m12 = mu1 * mu2;                                           \
        const float num = (2.f * m12 + C1v) * (2.f * (x12 - m12) + C2v);       \
        const float den = (mu1s + mu2s + C1v) *                                \
                          ((xs - mu1s - mu2s) + C2v);                          \
        local += num * __builtin_amdgcn_rcpf(den);                             \
    }

#define SSIM_PHASE(p)                                                          \
    if (y < yend) {                                                            \
        /* stage current row (regs -> LDS, masked zeros for x-pad) */          \
        lbuf[lane] = make_float2(pa0 * m0, pb0 * m0);                          \
        if (lane < 2 * PAD)                                                    \
            lbuf[WCOLS + lane] = make_float2(pa1 * m1, pb1 * m1);              \
        /* prefetch next row into regs (latency hidden under compute) */       \
        if (y + 1 < yend) {                                                    \
            rowA += IMG; rowB += IMG;                                          \
            pa0 = rowA[cc0]; pb0 = rowB[cc0];                                  \
            pa1 = rowA[cc1]; pb1 = rowB[cc1];                                  \
        }                                                                      \
        /* horizontal 11-tap blur of {a, b, a^2+b^2, ab} */                    \
        float h0 = 0.f, h1 = 0.f, h2 = 0.f, h3 = 0.f;                          \
        _Pragma("unroll")                                                      \
        for (int k = 0; k < KW; ++k) {                                         \
            const float2 ab = lbuf[lane + k];                                  \
            const float a = ab.x, b = ab.y;                                    \
            float sq = a * a;                                                  \
            sq = fmaf(b, b, sq);                                               \
            h0 += w[k] * a;                                                    \
            h1 += w[k] * b;                                                    \
            h2 += w[k] * sq;                                                   \
            h3 += w[k] * (a * b);                                              \
        }                                                                      \
        /* vertical scatter: input y -> outputs r=y-5+j, slot=(r-ystart)%11 */ \
        _Pragma("unroll")                                                      \
        for (int j = 0; j < KW; ++j) {                                         \
            const int sl = ((p) + 6 + j) % KW;                                 \
            const float wj = w[10 - j];                                        \
            acc0[sl] += wj * h0;                                               \
            acc1[sl] += wj * h1;                                               \
            acc2[sl] += wj * h2;                                               \
            acc3[sl] += wj * h3;                                               \
        }                                                                      \
        /* emit completed output row r = y-5 */                                \
        {                                                                      \
            const int sd = ((p) + 6) % KW;                                     \
            const int r = y - PAD;                                             \
            if (r >= y0) SSIM_EMIT(sd);                                        \
            acc0[sd] = 0.f; acc1[sd] = 0.f; acc2[sd] = 0.f; acc3[sd] = 0.f;    \
        }                                                                      \
        ++y;                                                                   \
    }

#pragma unroll 1
    for (int chunk = 0; chunk < NCHUNK; ++chunk) {
        SSIM_PHASE(0) SSIM_PHASE(1) SSIM_PHASE(2) SSIM_PHASE(3)
        SSIM_PHASE(4) SSIM_PHASE(5) SSIM_PHASE(6) SSIM_PHASE(7)
        SSIM_PHASE(8) SSIM_PHASE(9) SSIM_PHASE(10)
    }
#undef SSIM_PHASE

    // Bottom strip: rows 507..511 truncate at y=511; flush their slots.
    // ystart=443 -> slot(r)=(r-443)%11: 507->9, 508->10, 509->0, 510->1, 511->2.
    if (blockIdx.y == (IMG / SH - 1)) {
        SSIM_EMIT(9) SSIM_EMIT(10) SSIM_EMIT(0) SSIM_EMIT(1) SSIM_EMIT(2)
    }
#undef SSIM_EMIT

    // Per-wave reduction + one atomic per wave.
#pragma unroll
    for (int off = 32; off > 0; off >>= 1)
        local += __shfl_down(local, off);
    if (lane == 0)
        atomicAdd(accum, (double)local);
}

__global__ void ssim_finalize_kernel(const double* __restrict__ accum,
                                     float* __restrict__ out)
{
    const double N = (double)NPLANES * IMG * IMG;
    out[0] = (float)(1.0 - accum[0] / N);
}

extern "C" void kernel_launch(void* const* d_in, const int* in_sizes, int n_in,
                              void* d_out, int out_size, void* d_ws, size_t ws_size,
                              hipStream_t stream) {
    const float* img1 = (const float*)d_in[0];
    const float* img2 = (const float*)d_in[1];
    float* out = (float*)d_out;
    double* accum = (double*)d_ws;   // 8 bytes used

    // d_ws is poisoned 0xAA before every call — zero the accumulator.
    hipMemsetAsync(accum, 0, sizeof(double), stream);

    dim3 grid(IMG / BW, IMG / SH, NPLANES);   // 2 x 8 x 48 = 768 blocks
    ssim_wave_kernel<<<grid, BW, 0, stream>>>(img1, img2, accum);
    ssim_finalize_kernel<<<1, 1, 0, stream>>>(accum, out);
}